// Round 10
// baseline (102.635 us; speedup 1.0000x reference)
//
#include <hip/hip_runtime.h>
#include <hip/hip_bf16.h>
#include <stdint.h>

#define N_PTS 4096
#define DIM 512
#define MARGIN_F 0.3f
#define POS_INF_BITS 0x7f800000

typedef short bf16x8 __attribute__((ext_vector_type(8)));
typedef float f32x4 __attribute__((ext_vector_type(4)));

__device__ __forceinline__ unsigned short f2bf(float f) {
    unsigned int b = __float_as_uint(f);
    b += 0x7FFF + ((b >> 16) & 1);   // round-to-nearest-even
    return (unsigned short)(b >> 16);
}

// async global->LDS, 16B per lane; LDS dest is wave-uniform base + lane*16
__device__ __forceinline__ void async16(const unsigned short* g, unsigned short* l) {
    __builtin_amdgcn_global_load_lds(
        (const __attribute__((address_space(1))) unsigned int*)g,
        (__attribute__((address_space(3))) unsigned int*)l,
        16, 0, 0);
}

// Raw barrier / waitcnt (hipBLASLt pattern): no vmcnt(0) drain in steady state.
#define RAW_BARRIER()  asm volatile("s_barrier" ::: "memory")
#define WAIT_VM8()     asm volatile("s_waitcnt vmcnt(8)" ::: "memory")
#define WAIT_VM4()     asm volatile("s_waitcnt vmcnt(4)" ::: "memory")
#define WAIT_VM0()     asm volatile("s_waitcnt vmcnt(0)" ::: "memory")

// One wave per row: bf16 copy + exact fp32 norms; zero the output accumulator.
__global__ __launch_bounds__(256) void prep_kernel(
    const float* __restrict__ src, const float* __restrict__ tgt,
    unsigned short* __restrict__ src_bf, unsigned short* __restrict__ tgt_bf,
    float* __restrict__ e1, float* __restrict__ e2,
    float* __restrict__ out)
{
    const int row  = blockIdx.x * 4 + (threadIdx.x >> 6);
    const int lane = threadIdx.x & 63;

    if (blockIdx.x == 0 && threadIdx.x == 0) out[0] = 0.0f;

    const float4* s4 = (const float4*)(src + (size_t)row * DIM);
    const float4* t4 = (const float4*)(tgt + (size_t)row * DIM);
    float4 a0 = s4[lane], a1 = s4[lane + 64];
    float4 b0 = t4[lane], b1 = t4[lane + 64];

    ushort4 u;
    ushort4* so = (ushort4*)(src_bf + (size_t)row * DIM);
    ushort4* to = (ushort4*)(tgt_bf + (size_t)row * DIM);
    u.x = f2bf(a0.x); u.y = f2bf(a0.y); u.z = f2bf(a0.z); u.w = f2bf(a0.w); so[lane] = u;
    u.x = f2bf(a1.x); u.y = f2bf(a1.y); u.z = f2bf(a1.z); u.w = f2bf(a1.w); so[lane + 64] = u;
    u.x = f2bf(b0.x); u.y = f2bf(b0.y); u.z = f2bf(b0.z); u.w = f2bf(b0.w); to[lane] = u;
    u.x = f2bf(b1.x); u.y = f2bf(b1.y); u.z = f2bf(b1.z); u.w = f2bf(b1.w); to[lane + 64] = u;

    float s1 = a0.x*a0.x + a0.y*a0.y + a0.z*a0.z + a0.w*a0.w
             + a1.x*a1.x + a1.y*a1.y + a1.z*a1.z + a1.w*a1.w;
    float s2 = b0.x*b0.x + b0.y*b0.y + b0.z*b0.z + b0.w*b0.w
             + b1.x*b1.x + b1.y*b1.y + b1.z*b1.z + b1.w*b1.w;
    for (int off = 32; off; off >>= 1) {
        s1 += __shfl_down(s1, off);
        s2 += __shfl_down(s2, off);
    }
    if (lane == 0) {
        e1[row] = s1;
        e2[row] = s2;
    }
}

#define BM 128
#define BN 128
#define BK 32
#define NSTEP (DIM / BK)   // 16
#define NPART 64           // 32 col-blocks x 2 col-waves

// r9 + distance-2 prefetch (3-stage circular buffer):
//   step s: issue tile s+2 -> buf[(s+2)%3]; s_waitcnt vmcnt(8) (tile-s loads
//   were issued TWO compute phases ago — latency fully covered; the 8 newest
//   in-flight loads are tiles s+1/s+2); s_barrier; compute s; s_barrier.
// r9's distance-1 still exposed ~(L2 latency - 1 phase) per step; distance-2
// gives ~2 phases of cover. Lessons kept: no device fences (r4), no
// shared-line atomics (r6), XOR swizzle on the global gather (r3: 0
// conflicts), multi-block occupancy (r8: 1 block/CU cannot hide latency).
__global__ __launch_bounds__(256) void dist_kernel(
    const unsigned short* __restrict__ src_bf,
    const unsigned short* __restrict__ tgt_bf,
    const float* __restrict__ e1, const float* __restrict__ e2,
    const int* __restrict__ labels,
    float* __restrict__ ap_part, float* __restrict__ an_part)
{
    __shared__ unsigned short As[3][BM * BK];   // 3 x 8 KiB
    __shared__ unsigned short Bs[3][BN * BK];   // 3 x 8 KiB
    __shared__ int   li[BM];
    __shared__ int   lj[BN];
    __shared__ float e1s[BM];
    __shared__ float e2s[BN];

    const int i0 = blockIdx.y * BM;
    const int j0 = blockIdx.x * BN;
    const int t = threadIdx.x;
    const int lane = t & 63;
    const int wave = t >> 6;

    if (t < BM) { li[t] = labels[i0 + t]; e1s[t] = e1[i0 + t]; }
    else        { int u = t - BM; lj[u] = labels[j0 + u]; e2s[u] = e2[j0 + u]; }

    // staging: 512 16B-chunks per matrix per K-tile; thread t covers chunks
    // t (rows 0..63) and t+256 (rows 64..127). Physical chunk col = t&3 holds
    // logical chunk (t&3) ^ ((row>>1)&3); key identical for row and row+64.
    const int srow = t >> 2;                              // 0..63
    const int scol = ((t & 3) ^ ((srow >> 1) & 3)) * 8;   // swizzled source col
    const unsigned short* gA0 = src_bf + (size_t)(i0 + srow) * DIM + scol;
    const unsigned short* gA1 = src_bf + (size_t)(i0 + 64 + srow) * DIM + scol;
    const unsigned short* gB0 = tgt_bf + (size_t)(j0 + srow) * DIM + scol;
    const unsigned short* gB1 = tgt_bf + (size_t)(j0 + 64 + srow) * DIM + scol;
    const int ldsOff0 = wave * 512;          // chunk base wave*64
    const int ldsOff1 = 2048 + wave * 512;   // chunk base 256+wave*64

    // wave -> 64x64 subtile: 4x4 of 16x16x32 MFMA
    const int wm = (wave >> 1) * 64;
    const int wn = (wave & 1) * 64;
    const int fr = lane & 15;
    const int quad = lane >> 4;
    const int fkey = (fr >> 1) & 3;                       // read-side XOR key
    const int cp = (quad ^ fkey) * 8;                     // physical chunk off

    f32x4 acc[4][4];
    #pragma unroll
    for (int a = 0; a < 4; a++)
        #pragma unroll
        for (int b = 0; b < 4; b++)
            acc[a][b] = (f32x4){0.f, 0.f, 0.f, 0.f};

    // prologue: tiles 0 and 1 -> bufs 0,1 (8 loads in flight)
    #pragma unroll
    for (int p = 0; p < 2; p++) {
        const int kk = p * BK;
        async16(gA0 + kk, &As[p][0] + ldsOff0);
        async16(gA1 + kk, &As[p][0] + ldsOff1);
        async16(gB0 + kk, &Bs[p][0] + ldsOff0);
        async16(gB1 + kk, &Bs[p][0] + ldsOff1);
    }

    #pragma unroll
    for (int s = 0; s < NSTEP; s++) {
        if (s + 2 < NSTEP) {
            const int kk = (s + 2) * BK;
            const int nb = (s + 2) % 3;
            async16(gA0 + kk, &As[nb][0] + ldsOff0);
            async16(gA1 + kk, &As[nb][0] + ldsOff1);
            async16(gB0 + kk, &Bs[nb][0] + ldsOff0);
            async16(gB1 + kk, &Bs[nb][0] + ldsOff1);
            WAIT_VM8();    // tile-s loads (2 phases old) done; s+1/s+2 fly
        } else if (s + 2 == NSTEP) {
            WAIT_VM4();    // tile s done; only tile s+1's 4 loads in flight
        } else {
            WAIT_VM0();    // last tile
        }
        RAW_BARRIER();     // all waves' tile-s DMA landed

        const unsigned short* aa = &As[s % 3][0];
        const unsigned short* bb = &Bs[s % 3][0];
        bf16x8 af[4], bf[4];
        #pragma unroll
        for (int x = 0; x < 4; x++) {
            af[x] = *(const bf16x8*)&aa[(wm + x * 16 + fr) * BK + cp];
            bf[x] = *(const bf16x8*)&bb[(wn + x * 16 + fr) * BK + cp];
        }
        #pragma unroll
        for (int tm = 0; tm < 4; tm++)
            #pragma unroll
            for (int tn = 0; tn < 4; tn++)
                acc[tm][tn] = __builtin_amdgcn_mfma_f32_16x16x32_bf16(
                    af[tm], bf[tn], acc[tm][tn], 0, 0, 0);

        if (s + 1 < NSTEP)
            RAW_BARRIER(); // all reads of buf s%3 done -> s+3 may overwrite it
    }

    // epilogue: dist -> masked row max/min -> 16-lane reduce -> partial store
    const float INF = __int_as_float(POS_INF_BITS);
    const int pcol = blockIdx.x * 2 + (wave & 1);        // per-col-wave slot
    #pragma unroll
    for (int tm = 0; tm < 4; tm++) {
        #pragma unroll
        for (int r = 0; r < 4; r++) {
            const int rl = wm + tm * 16 + quad * 4 + r;  // local row
            const float e1v = e1s[rl];
            const int   liv = li[rl];
            float apv = 0.0f;   // neutral for max (dist >= 0)
            float anv = INF;
            #pragma unroll
            for (int tn = 0; tn < 4; tn++) {
                const int cl = wn + tn * 16 + fr;        // local col
                float d = e1v + e2s[cl] - 2.0f * acc[tm][tn][r];
                d = fmaxf(d, 0.0f);
                if (liv == lj[cl]) apv = fmaxf(apv, d);
                else               anv = fminf(anv, d);
            }
            #pragma unroll
            for (int off = 1; off < 16; off <<= 1) {
                apv = fmaxf(apv, __shfl_xor(apv, off));
                anv = fminf(anv, __shfl_xor(anv, off));
            }
            if (fr == 0) {
                ap_part[(size_t)(i0 + rl) * NPART + pcol] = apv;
                an_part[(size_t)(i0 + rl) * NPART + pcol] = anv;
            }
        }
    }
}

// 32 blocks x 128 threads; thread = one row: reduce 64 partials, relu, sum.
__global__ __launch_bounds__(128) void loss_kernel(
    const float* __restrict__ ap_part, const float* __restrict__ an_part,
    float* __restrict__ out)
{
    const int row = blockIdx.x * 128 + threadIdx.x;
    const float4* a4 = (const float4*)(ap_part + (size_t)row * NPART);
    const float4* n4 = (const float4*)(an_part + (size_t)row * NPART);
    float apv = 0.0f;
    float anv = __int_as_float(POS_INF_BITS);
    #pragma unroll
    for (int i = 0; i < NPART / 4; i++) {
        float4 a = a4[i], n = n4[i];
        apv = fmaxf(apv, fmaxf(fmaxf(a.x, a.y), fmaxf(a.z, a.w)));
        anv = fminf(anv, fminf(fminf(n.x, n.y), fminf(n.z, n.w)));
    }
    float s = fmaxf(apv - anv + MARGIN_F, 0.0f);
    for (int off = 32; off; off >>= 1) s += __shfl_down(s, off);
    __shared__ float red[2];
    if ((threadIdx.x & 63) == 0) red[threadIdx.x >> 6] = s;
    __syncthreads();
    if (threadIdx.x == 0)
        atomicAdd(out, (red[0] + red[1]) / (float)N_PTS);
}

extern "C" void kernel_launch(void* const* d_in, const int* in_sizes, int n_in,
                              void* d_out, int out_size, void* d_ws, size_t ws_size,
                              hipStream_t stream) {
    const float* src   = (const float*)d_in[0];
    const float* tgt   = (const float*)d_in[1];
    const int* labels  = (const int*)d_in[2];

    char* ws = (char*)d_ws;
    const size_t featB = (size_t)N_PTS * DIM * sizeof(unsigned short);  // 4 MiB
    unsigned short* src_bf = (unsigned short*)ws;
    unsigned short* tgt_bf = (unsigned short*)(ws + featB);
    float* e1 = (float*)(ws + 2 * featB);
    float* e2 = e1 + N_PTS;
    float* ap_part = e2 + N_PTS;                 // [N_PTS][NPART] = 1 MiB
    float* an_part = ap_part + (size_t)N_PTS * NPART;

    prep_kernel<<<N_PTS / 4, 256, 0, stream>>>(src, tgt, src_bf, tgt_bf,
                                               e1, e2, (float*)d_out);
    dim3 grid(N_PTS / BN, N_PTS / BM);
    dist_kernel<<<grid, 256, 0, stream>>>(src_bf, tgt_bf, e1, e2, labels,
                                          ap_part, an_part);
    loss_kernel<<<N_PTS / 128, 128, 0, stream>>>(ap_part, an_part, (float*)d_out);
}

// Round 11
// 100.076 us; speedup vs baseline: 1.0256x; 1.0256x over previous
//
#include <hip/hip_runtime.h>
#include <hip/hip_bf16.h>
#include <stdint.h>

#define N_PTS 4096
#define DIM 512
#define MARGIN_F 0.3f
#define POS_INF_BITS 0x7f800000

typedef short bf16x8 __attribute__((ext_vector_type(8)));
typedef float f32x4 __attribute__((ext_vector_type(4)));

__device__ __forceinline__ unsigned short f2bf(float f) {
    unsigned int b = __float_as_uint(f);
    b += 0x7FFF + ((b >> 16) & 1);   // round-to-nearest-even
    return (unsigned short)(b >> 16);
}

// async global->LDS, 16B per lane; LDS dest is wave-uniform base + lane*16
__device__ __forceinline__ void async16(const unsigned short* g, unsigned short* l) {
    __builtin_amdgcn_global_load_lds(
        (const __attribute__((address_space(1))) unsigned int*)g,
        (__attribute__((address_space(3))) unsigned int*)l,
        16, 0, 0);
}

// Raw barrier / waitcnt (hipBLASLt pattern): no vmcnt(0) drain in steady state.
#define RAW_BARRIER()  asm volatile("s_barrier" ::: "memory")
#define WAIT_VM12()    asm volatile("s_waitcnt vmcnt(12)" ::: "memory")
#define WAIT_VM6()     asm volatile("s_waitcnt vmcnt(6)" ::: "memory")
#define WAIT_VM0()     asm volatile("s_waitcnt vmcnt(0)" ::: "memory")

// One wave per row: bf16 copy + exact fp32 norms; zero the output accumulator.
__global__ __launch_bounds__(256) void prep_kernel(
    const float* __restrict__ src, const float* __restrict__ tgt,
    unsigned short* __restrict__ src_bf, unsigned short* __restrict__ tgt_bf,
    float* __restrict__ e1, float* __restrict__ e2,
    float* __restrict__ out)
{
    const int row  = blockIdx.x * 4 + (threadIdx.x >> 6);
    const int lane = threadIdx.x & 63;

    if (blockIdx.x == 0 && threadIdx.x == 0) out[0] = 0.0f;

    const float4* s4 = (const float4*)(src + (size_t)row * DIM);
    const float4* t4 = (const float4*)(tgt + (size_t)row * DIM);
    float4 a0 = s4[lane], a1 = s4[lane + 64];
    float4 b0 = t4[lane], b1 = t4[lane + 64];

    ushort4 u;
    ushort4* so = (ushort4*)(src_bf + (size_t)row * DIM);
    ushort4* to = (ushort4*)(tgt_bf + (size_t)row * DIM);
    u.x = f2bf(a0.x); u.y = f2bf(a0.y); u.z = f2bf(a0.z); u.w = f2bf(a0.w); so[lane] = u;
    u.x = f2bf(a1.x); u.y = f2bf(a1.y); u.z = f2bf(a1.z); u.w = f2bf(a1.w); so[lane + 64] = u;
    u.x = f2bf(b0.x); u.y = f2bf(b0.y); u.z = f2bf(b0.z); u.w = f2bf(b0.w); to[lane] = u;
    u.x = f2bf(b1.x); u.y = f2bf(b1.y); u.z = f2bf(b1.z); u.w = f2bf(b1.w); to[lane + 64] = u;

    float s1 = a0.x*a0.x + a0.y*a0.y + a0.z*a0.z + a0.w*a0.w
             + a1.x*a1.x + a1.y*a1.y + a1.z*a1.z + a1.w*a1.w;
    float s2 = b0.x*b0.x + b0.y*b0.y + b0.z*b0.z + b0.w*b0.w
             + b1.x*b1.x + b1.y*b1.y + b1.z*b1.z + b1.w*b1.w;
    for (int off = 32; off; off >>= 1) {
        s1 += __shfl_down(s1, off);
        s2 += __shfl_down(s2, off);
    }
    if (lane == 0) {
        e1[row] = s1;
        e2[row] = s2;
    }
}

#define BM 128
#define BN 256
#define BK 32
#define NSTEP (DIM / BK)   // 16
#define NPART 64           // 16 col-blocks x 4 col-waves

// Fat-wave tiling: per-wave 128x64 (8x4 MFMA tiles), block 128x256, 512
// blocks = exactly 2/CU, no tail. Rationale (r10 post-mortem): LDS read
// traffic per output area ~ waves*(m+n); 4x(128+64) beats 4x(64+64) by
// 0.75x, and the per-step cycle balance flips to MFMA-bound (128 MFMA
// ~620 cyc vs 48 ds_read_b128 ~576 cyc). 3-stage distance-2 raw pipeline
// kept (6 async16/step -> steady-state s_waitcnt vmcnt(12), never 0).
// Lessons kept: no device fences (r4), no shared-line atomics (r6), XOR
// swizzle on the global gather (r3/r9: 0 conflicts), multi-block/CU (r8).
__global__ __launch_bounds__(256, 2) void dist_kernel(
    const unsigned short* __restrict__ src_bf,
    const unsigned short* __restrict__ tgt_bf,
    const float* __restrict__ e1, const float* __restrict__ e2,
    const int* __restrict__ labels,
    float* __restrict__ ap_part, float* __restrict__ an_part)
{
    __shared__ unsigned short As[3][BM * BK];   // 3 x 8 KiB
    __shared__ unsigned short Bs[3][BN * BK];   // 3 x 16 KiB
    __shared__ int   li[BM];
    __shared__ int   lj[BN];
    __shared__ float e1s[BM];
    __shared__ float e2s[BN];

    const int i0 = blockIdx.y * BM;
    const int j0 = blockIdx.x * BN;
    const int t = threadIdx.x;
    const int lane = t & 63;
    const int wave = t >> 6;

    lj[t] = labels[j0 + t];
    e2s[t] = e2[j0 + t];
    if (t < BM) { li[t] = labels[i0 + t]; e1s[t] = e1[i0 + t]; }

    // staging: 16B chunks; thread t covers A rows srow, srow+64 and B rows
    // srow, +64, +128, +192. Physical chunk col t&3 holds logical chunk
    // (t&3)^((srow>>1)&3) (same swizzle key for row and row+64k).
    const int srow = t >> 2;                              // 0..63
    const int scol = ((t & 3) ^ ((srow >> 1) & 3)) * 8;   // swizzled source col
    const unsigned short* gA0 = src_bf + (size_t)(i0 + srow) * DIM + scol;
    const unsigned short* gA1 = src_bf + (size_t)(i0 + 64 + srow) * DIM + scol;
    const unsigned short* gB0 = tgt_bf + (size_t)(j0 + srow) * DIM + scol;
    const unsigned short* gB1 = tgt_bf + (size_t)(j0 + 64 + srow) * DIM + scol;
    const unsigned short* gB2 = tgt_bf + (size_t)(j0 + 128 + srow) * DIM + scol;
    const unsigned short* gB3 = tgt_bf + (size_t)(j0 + 192 + srow) * DIM + scol;
    const int aOff0 = wave * 512;            // A rows 0..63 chunk base
    const int aOff1 = 2048 + wave * 512;     // A rows 64..127
    const int bOff0 = wave * 512;            // B rows 0..63
    const int bOff1 = 2048 + wave * 512;     // 64..127
    const int bOff2 = 4096 + wave * 512;     // 128..191
    const int bOff3 = 6144 + wave * 512;     // 192..255

    // wave -> 128x64 subtile: 8x4 of 16x16x32 MFMA; wn = wave*64
    const int wn = wave * 64;
    const int fr = lane & 15;
    const int quad = lane >> 4;
    const int fkey = (fr >> 1) & 3;                       // read-side XOR key
    const int cp = (quad ^ fkey) * 8;                     // physical chunk off

    f32x4 acc[8][4];
    #pragma unroll
    for (int a = 0; a < 8; a++)
        #pragma unroll
        for (int b = 0; b < 4; b++)
            acc[a][b] = (f32x4){0.f, 0.f, 0.f, 0.f};

    // prologue: tiles 0 and 1 -> bufs 0,1 (12 loads in flight)
    #pragma unroll
    for (int p = 0; p < 2; p++) {
        const int kk = p * BK;
        async16(gA0 + kk, &As[p][0] + aOff0);
        async16(gA1 + kk, &As[p][0] + aOff1);
        async16(gB0 + kk, &Bs[p][0] + bOff0);
        async16(gB1 + kk, &Bs[p][0] + bOff1);
        async16(gB2 + kk, &Bs[p][0] + bOff2);
        async16(gB3 + kk, &Bs[p][0] + bOff3);
    }

    #pragma unroll
    for (int s = 0; s < NSTEP; s++) {
        if (s + 2 < NSTEP) {
            const int kk = (s + 2) * BK;
            const int nb = (s + 2) % 3;
            async16(gA0 + kk, &As[nb][0] + aOff0);
            async16(gA1 + kk, &As[nb][0] + aOff1);
            async16(gB0 + kk, &Bs[nb][0] + bOff0);
            async16(gB1 + kk, &Bs[nb][0] + bOff1);
            async16(gB2 + kk, &Bs[nb][0] + bOff2);
            async16(gB3 + kk, &Bs[nb][0] + bOff3);
            WAIT_VM12();   // tile-s loads (2 phases old) done; s+1/s+2 fly
        } else if (s + 2 == NSTEP) {
            WAIT_VM6();    // tile s done; only tile s+1's 6 loads in flight
        } else {
            WAIT_VM0();    // last tile
        }
        RAW_BARRIER();     // all waves' tile-s DMA landed

        const unsigned short* aa = &As[s % 3][0];
        const unsigned short* bb = &Bs[s % 3][0];
        bf16x8 af[8], bf[4];
        #pragma unroll
        for (int x = 0; x < 8; x++)
            af[x] = *(const bf16x8*)&aa[(x * 16 + fr) * BK + cp];
        #pragma unroll
        for (int x = 0; x < 4; x++)
            bf[x] = *(const bf16x8*)&bb[(wn + x * 16 + fr) * BK + cp];
        #pragma unroll
        for (int tm = 0; tm < 8; tm++)
            #pragma unroll
            for (int tn = 0; tn < 4; tn++)
                acc[tm][tn] = __builtin_amdgcn_mfma_f32_16x16x32_bf16(
                    af[tm], bf[tn], acc[tm][tn], 0, 0, 0);

        if (s + 1 < NSTEP)
            RAW_BARRIER(); // all reads of buf s%3 done -> step s+1 may refill it
    }

    // epilogue: dist -> masked row max/min -> 16-lane reduce -> partial store
    const float INF = __int_as_float(POS_INF_BITS);
    const int pcol = blockIdx.x * 4 + wave;              // per-col-wave slot
    #pragma unroll
    for (int tm = 0; tm < 8; tm++) {
        #pragma unroll
        for (int r = 0; r < 4; r++) {
            const int rl = tm * 16 + quad * 4 + r;       // local row 0..127
            const float e1v = e1s[rl];
            const int   liv = li[rl];
            float apv = 0.0f;   // neutral for max (dist >= 0)
            float anv = INF;
            #pragma unroll
            for (int tn = 0; tn < 4; tn++) {
                const int cl = wn + tn * 16 + fr;        // local col 0..255
                float d = e1v + e2s[cl] - 2.0f * acc[tm][tn][r];
                d = fmaxf(d, 0.0f);
                if (liv == lj[cl]) apv = fmaxf(apv, d);
                else               anv = fminf(anv, d);
            }
            #pragma unroll
            for (int off = 1; off < 16; off <<= 1) {
                apv = fmaxf(apv, __shfl_xor(apv, off));
                anv = fminf(anv, __shfl_xor(anv, off));
            }
            if (fr == 0) {
                ap_part[(size_t)(i0 + rl) * NPART + pcol] = apv;
                an_part[(size_t)(i0 + rl) * NPART + pcol] = anv;
            }
        }
    }
}

// 32 blocks x 128 threads; thread = one row: reduce 64 partials, relu, sum.
__global__ __launch_bounds__(128) void loss_kernel(
    const float* __restrict__ ap_part, const float* __restrict__ an_part,
    float* __restrict__ out)
{
    const int row = blockIdx.x * 128 + threadIdx.x;
    const float4* a4 = (const float4*)(ap_part + (size_t)row * NPART);
    const float4* n4 = (const float4*)(an_part + (size_t)row * NPART);
    float apv = 0.0f;
    float anv = __int_as_float(POS_INF_BITS);
    #pragma unroll
    for (int i = 0; i < NPART / 4; i++) {
        float4 a = a4[i], n = n4[i];
        apv = fmaxf(apv, fmaxf(fmaxf(a.x, a.y), fmaxf(a.z, a.w)));
        anv = fminf(anv, fminf(fminf(n.x, n.y), fminf(n.z, n.w)));
    }
    float s = fmaxf(apv - anv + MARGIN_F, 0.0f);
    for (int off = 32; off; off >>= 1) s += __shfl_down(s, off);
    __shared__ float red[2];
    if ((threadIdx.x & 63) == 0) red[threadIdx.x >> 6] = s;
    __syncthreads();
    if (threadIdx.x == 0)
        atomicAdd(out, (red[0] + red[1]) / (float)N_PTS);
}

extern "C" void kernel_launch(void* const* d_in, const int* in_sizes, int n_in,
                              void* d_out, int out_size, void* d_ws, size_t ws_size,
                              hipStream_t stream) {
    const float* src   = (const float*)d_in[0];
    const float* tgt   = (const float*)d_in[1];
    const int* labels  = (const int*)d_in[2];

    char* ws = (char*)d_ws;
    const size_t featB = (size_t)N_PTS * DIM * sizeof(unsigned short);  // 4 MiB
    unsigned short* src_bf = (unsigned short*)ws;
    unsigned short* tgt_bf = (unsigned short*)(ws + featB);
    float* e1 = (float*)(ws + 2 * featB);
    float* e2 = e1 + N_PTS;
    float* ap_part = e2 + N_PTS;                 // [N_PTS][NPART] = 1 MiB
    float* an_part = ap_part + (size_t)N_PTS * NPART;

    prep_kernel<<<N_PTS / 4, 256, 0, stream>>>(src, tgt, src_bf, tgt_bf,
                                               e1, e2, (float*)d_out);
    dim3 grid(N_PTS / BN, N_PTS / BM);
    dist_kernel<<<grid, 256, 0, stream>>>(src_bf, tgt_bf, e1, e2, labels,
                                          ap_part, an_part);
    loss_kernel<<<N_PTS / 128, 128, 0, stream>>>(ap_part, an_part, (float*)d_out);
}